// Round 1
// baseline (82.061 us; speedup 1.0000x reference)
//
#include <hip/hip_runtime.h>

// ST-BIF multi-step neuron, collapsed to an elementwise kernel.
// Each element: unroll T=8 steps of integrate/fire/reset; output acc/8.
// Memory-bound: 2 x 25.7 MB traffic -> ~8 us roofline at 6.3 TB/s.

constexpr int T_STEPS = 8;
constexpr float T_MAX = 8.0f;   // +LEVEL
constexpr float T_MIN = -8.0f;  // -LEVEL

__device__ __forceinline__ float stbif_elem(float x, float vth) {
    float v = 0.0f, cnt = 0.0f, acc = 0.0f;
#pragma unroll
    for (int t = 0; t < T_STEPS; ++t) {
        float h = v + x;
        // fire_pos has priority (matches jnp.where nesting)
        float spike = (h >= vth && cnt < T_MAX) ? 1.0f
                    : ((h < 0.0f && cnt > T_MIN) ? -1.0f : 0.0f);
        v = h - spike * vth;
        cnt += spike;
        acc += spike * vth;
    }
    return acc * (1.0f / (float)T_STEPS);
}

__global__ void __launch_bounds__(256) stbif_vec4_kernel(
    const float4* __restrict__ x, const float* __restrict__ vth_ptr,
    float4* __restrict__ out, int n4) {
    int i = blockIdx.x * blockDim.x + threadIdx.x;
    if (i >= n4) return;
    const float vth = *vth_ptr;  // scalar, L1/L2 broadcast
    float4 xv = x[i];
    float4 ov;
    ov.x = stbif_elem(xv.x, vth);
    ov.y = stbif_elem(xv.y, vth);
    ov.z = stbif_elem(xv.z, vth);
    ov.w = stbif_elem(xv.w, vth);
    out[i] = ov;
}

__global__ void stbif_tail_kernel(const float* __restrict__ x,
                                  const float* __restrict__ vth_ptr,
                                  float* __restrict__ out, int start, int n) {
    int i = start + blockIdx.x * blockDim.x + threadIdx.x;
    if (i >= n) return;
    out[i] = stbif_elem(x[i], *vth_ptr);
}

extern "C" void kernel_launch(void* const* d_in, const int* in_sizes, int n_in,
                              void* d_out, int out_size, void* d_ws, size_t ws_size,
                              hipStream_t stream) {
    const float* x   = (const float*)d_in[0];
    const float* vth = (const float*)d_in[1];
    float* out = (float*)d_out;
    int n = in_sizes[0];

    int n4 = n / 4;
    if (n4 > 0) {
        int blocks = (n4 + 255) / 256;
        stbif_vec4_kernel<<<blocks, 256, 0, stream>>>(
            (const float4*)x, vth, (float4*)out, n4);
    }
    int rem = n - n4 * 4;
    if (rem > 0) {
        stbif_tail_kernel<<<1, 256, 0, stream>>>(x, vth, out, n4 * 4, n);
    }
}

// Round 2
// 79.875 us; speedup vs baseline: 1.0274x; 1.0274x over previous
//
#include <hip/hip_runtime.h>

// ST-BIF multi-step neuron, collapsed to an elementwise kernel.
//
// Key simplification (exactness argument in journal): with T=8 steps and
// level=8, the spike counter can never hit the clamp (|cnt| <= t-1 <= 7 < 8
// before any step), and fire_pos/fire_neg are mutually exclusive
// (h >= vth vs h < 0). So cnt and its 4 ops/step are dead. Each step is:
//   h = v + x; d = (h>=vth) ? vth : (h<0 ? -vth : 0); v = h - d; acc += d;
// which is bit-exact vs the reference scan (d == spike*vth exactly).
//
// Memory-bound target: 2 x 25.7 MB traffic -> ~8 us at 6.3 TB/s.

constexpr int T_STEPS = 8;

__device__ __forceinline__ float stbif_elem(float x, float vth) {
    float v = 0.0f, acc = 0.0f;
#pragma unroll
    for (int t = 0; t < T_STEPS; ++t) {
        float h = v + x;
        // fire_pos priority; mutually exclusive with fire_neg, cnt clamp dead.
        float d = (h >= vth) ? vth : ((h < 0.0f) ? -vth : 0.0f);
        v = h - d;
        acc += d;
    }
    return acc * 0.125f;  // /8 exact (power of two)
}

__global__ void __launch_bounds__(256) stbif_vec4_kernel(
    const float4* __restrict__ x, const float* __restrict__ vth_ptr,
    float4* __restrict__ out, int n4) {
    int i = blockIdx.x * blockDim.x + threadIdx.x;
    if (i >= n4) return;
    const float vth = *vth_ptr;  // uniform scalar load
    float4 xv = x[i];
    float4 ov;
    ov.x = stbif_elem(xv.x, vth);
    ov.y = stbif_elem(xv.y, vth);
    ov.z = stbif_elem(xv.z, vth);
    ov.w = stbif_elem(xv.w, vth);
    out[i] = ov;
}

__global__ void stbif_tail_kernel(const float* __restrict__ x,
                                  const float* __restrict__ vth_ptr,
                                  float* __restrict__ out, int start, int n) {
    int i = start + blockIdx.x * blockDim.x + threadIdx.x;
    if (i >= n) return;
    out[i] = stbif_elem(x[i], *vth_ptr);
}

extern "C" void kernel_launch(void* const* d_in, const int* in_sizes, int n_in,
                              void* d_out, int out_size, void* d_ws, size_t ws_size,
                              hipStream_t stream) {
    const float* x   = (const float*)d_in[0];
    const float* vth = (const float*)d_in[1];
    float* out = (float*)d_out;
    int n = in_sizes[0];

    int n4 = n / 4;
    if (n4 > 0) {
        int blocks = (n4 + 255) / 256;
        stbif_vec4_kernel<<<blocks, 256, 0, stream>>>(
            (const float4*)x, vth, (float4*)out, n4);
    }
    int rem = n - n4 * 4;
    if (rem > 0) {
        stbif_tail_kernel<<<1, 256, 0, stream>>>(x, vth, out, n4 * 4, n);
    }
}